// Round 4
// baseline (682.084 us; speedup 1.0000x reference)
//
#include <hip/hip_runtime.h>
#include <math.h>

// Problem constants (B=C=1)
#define NPAT 27          // 3^3 patches
#define PATCH 110592     // 48^3 voxels per patch
#define VOL 884736       // 96^3 grid voxels

#define XT 12            // x tile dim (8 + 2*2 halo)
#define YT 10            // y1 tile dim (8 + 2*1 halo)
#define YW 11            // y1 tile w stride (odd: bank-conflict-free)
#define CGRP 8           // conv1 channels per LDS pass (16 = 2 passes)

__device__ __forceinline__ float softplusf(float a) {
    // stable softplus = max(a,0) + log1p(exp(-|a|)) — matches jax.nn.softplus
    return fmaxf(a, 0.f) + log1pf(expf(-fabsf(a)));
}

// One full Gauss-Seidel sweep over the 27 patches, fused with extract().
// One thread per patch-voxel p. i-loop fully unrolled -> cur[27] in REGISTERS
// (zero LDS). Double-buffered prefetch of row i+1's 27 A-values keeps >=27
// loads in flight per wave through each compute+wait phase, so the A stream
// (322.5 MB/sweep, nontemporal) runs at HBM rate instead of serializing on a
// per-iteration vmcnt(0) drain.
__global__ __launch_bounds__(256) void gs_sweep(
    const float* __restrict__ xf, const float* __restrict__ bg,
    const float* __restrict__ A, float* __restrict__ cur_out)
{
    const int p = blockIdx.x * 256 + threadIdx.x;  // grid = PATCH/256 = 432
    const int pd = p / 2304;                       // 48*48
    const int r0 = p - pd * 2304;
    const int ph = r0 / 48;
    const int pw = r0 - ph * 48;
    const int gbase = (pd * 96 + ph) * 96 + pw;    // global idx of patch (0,0,0)

    // extract(): cur[n] = x_field at lin(n,p); coalesced per n (pw contiguous)
    float cur[NPAT];
#pragma unroll
    for (int n = 0; n < NPAT; ++n) {
        const int nd = n / 9, nh = (n / 3) % 3, nw = n % 3;
        cur[n] = xf[gbase + nd * 221184 + nh * 2304 + nw * 24];
    }

    const float* Ap = A + p;
    float a_cur[NPAT], a_nxt[NPAT];
#pragma unroll
    for (int n = 0; n < NPAT; ++n)
        a_cur[n] = __builtin_nontemporal_load(&Ap[(size_t)n * PATCH]);
    float b_cur = bg[gbase];   // row 0 b (n=0 offset is 0)
    float b_nxt = 0.f;

#pragma unroll
    for (int i = 0; i < NPAT; ++i) {
        // prefetch row i+1 while row i computes
        if (i + 1 < NPAT) {
            const float* An = Ap + (size_t)(i + 1) * (NPAT * PATCH);
#pragma unroll
            for (int n = 0; n < NPAT; ++n)
                a_nxt[n] = __builtin_nontemporal_load(&An[(size_t)n * PATCH]);
            const int jd = (i + 1) / 9, jh = ((i + 1) / 3) % 3, jw = (i + 1) % 3;
            b_nxt = bg[gbase + jd * 221184 + jh * 2304 + jw * 24];
        }
        float cross = 0.f;
#pragma unroll
        for (int n = 0; n < NPAT; ++n)
            cross += a_cur[n] * cur[n];
        const float aii = a_cur[i];
        const float coupling = cross - aii * cur[i];
        cur[i] = (b_cur - coupling) / (softplusf(aii) + 1e-8f);
        // buffer swap: register renames under full unroll (no real moves)
#pragma unroll
        for (int n = 0; n < NPAT; ++n)
            a_cur[n] = a_nxt[n];
        b_cur = b_nxt;
    }

#pragma unroll
    for (int n = 0; n < NPAT; ++n)
        cur_out[(size_t)n * PATCH + p] = cur[n];
}

// Fused reconstruct + conv1 + relu + conv2; y1 only in LDS.
// Channel-split: 16 conv1 channels in 2 passes of 8 -> ys LDS halves
// (total 42.1 KB -> 3 blocks/CU instead of 2). conv2 accumulators live in
// registers across passes.
__global__ __launch_bounds__(256) void fused_conv(
    const float* __restrict__ curp,
    const float* __restrict__ w1, const float* __restrict__ b1,
    const float* __restrict__ w2, const float* __restrict__ b2,
    float* __restrict__ out)
{
    __shared__ float xs[XT * XT * XT];            // 6.75 KB
    __shared__ float ys[CGRP * YT * YT * YW];     // 34.4 KB
    const int tid = threadIdx.x;
    const int bw = blockIdx.x % 12;
    const int bh = (blockIdx.x / 12) % 12;
    const int bd = blockIdx.x / 144;
    const int d0 = bd * 8, h0 = bh * 8, w0 = bw * 8;

    // ---- stage 1: reconstruct() into x tile (+halo 2), zero outside volume ----
    for (int l = tid; l < XT * XT * XT; l += 256) {
        const int ld = l / (XT * XT);
        const int r = l - ld * XT * XT;
        const int lh = r / XT, lw = r - lh * XT;
        const int gd = d0 + ld - 2, gh = h0 + lh - 2, gw = w0 + lw - 2;
        float v = 0.f;
        if ((unsigned)gd < 96u && (unsigned)gh < 96u && (unsigned)gw < 96u) {
            const int dlo = max(0, gd / 24 - 1), dhi = min(2, gd / 24);
            const int hlo = max(0, gh / 24 - 1), hhi = min(2, gh / 24);
            const int wlo = max(0, gw / 24 - 1), whi = min(2, gw / 24);
            float sum = 0.f;
            for (int nd = dlo; nd <= dhi; ++nd)
                for (int nh = hlo; nh <= hhi; ++nh)
                    for (int nw = wlo; nw <= whi; ++nw) {
                        const int n = nd * 9 + nh * 3 + nw;
                        const int pp = (gd - 24 * nd) * 2304 +
                                       (gh - 24 * nh) * 48 + (gw - 24 * nw);
                        sum += curp[(size_t)n * PATCH + pp];
                    }
            const int cnt = (dhi - dlo + 1) * (hhi - hlo + 1) * (whi - wlo + 1);
            v = sum / (float)cnt;
        }
        xs[l] = v;
    }

    // strip decomposition for stage 2 (200 threads, 5-wide strips)
    const int sd = tid / 20;
    const int rr = tid - sd * 20;
    const int sh = rr >> 1;
    const int sw0 = (rr & 1) * 5;
    // strip decomposition for stage 3 (128 threads, 4-wide strips)
    const int ow0 = (tid & 1) * 4;
    const int oh = (tid >> 1) & 7;
    const int od = tid >> 4;

    const float bb2 = b2[0];
    float a0 = bb2, a1 = bb2, a2 = bb2, a3 = bb2;

    // x window registers for stage 2, loaded once and reused by both passes
    float xv[63];
    float msk[5];
    if (tid < 200) {
        // out-of-volume y1 positions must be ZERO (conv2's zero padding)
        const int gdq = d0 + sd - 1, ghq = h0 + sh - 1;
        const bool okdh = ((unsigned)gdq < 96u) && ((unsigned)ghq < 96u);
#pragma unroll
        for (int j = 0; j < 5; ++j)
            msk[j] = (okdh && (unsigned)(w0 + sw0 + j - 1) < 96u) ? 1.f : 0.f;
    }
    __syncthreads();
    if (tid < 200) {
#pragma unroll
        for (int kd = 0; kd < 3; ++kd)
#pragma unroll
            for (int kh = 0; kh < 3; ++kh)
#pragma unroll
                for (int j = 0; j < 7; ++j)
                    xv[(kd * 3 + kh) * 7 + j] =
                        xs[((sd + kd) * XT + (sh + kh)) * XT + sw0 + j];
    }

#pragma unroll 1
    for (int grp = 0; grp < 2; ++grp) {
        // ---- stage 2: ys = relu(conv1(x)) for channels [grp*8, grp*8+8) ----
        if (tid < 200) {
#pragma unroll 1
            for (int cc = 0; cc < CGRP; ++cc) {
                const int c = grp * CGRP + cc;
                float wr[27];
#pragma unroll
                for (int k = 0; k < 27; ++k) wr[k] = w1[c * 27 + k];
                const float bb = b1[c];
                float acc[5] = {bb, bb, bb, bb, bb};
#pragma unroll
                for (int kd = 0; kd < 3; ++kd)
#pragma unroll
                    for (int kh = 0; kh < 3; ++kh)
#pragma unroll
                        for (int kw = 0; kw < 3; ++kw) {
                            const float wgt = wr[kd * 9 + kh * 3 + kw];
                            const float* xvr = &xv[(kd * 3 + kh) * 7 + kw];
#pragma unroll
                            for (int j = 0; j < 5; ++j)
                                acc[j] += wgt * xvr[j];
                        }
                float* yrow = &ys[((cc * YT + sd) * YT + sh) * YW + sw0];
#pragma unroll
                for (int j = 0; j < 5; ++j)
                    yrow[j] = fmaxf(acc[j], 0.f) * msk[j];
            }
        }
        __syncthreads();

        // ---- stage 3: accumulate conv2 over this channel group ----
        if (tid < 128) {
#pragma unroll 1
            for (int cc = 0; cc < CGRP; ++cc) {
                const int c = grp * CGRP + cc;
                float wr[27];
#pragma unroll
                for (int k = 0; k < 27; ++k) wr[k] = w2[c * 27 + k];
#pragma unroll
                for (int kd = 0; kd < 3; ++kd)
#pragma unroll
                    for (int kh = 0; kh < 3; ++kh) {
                        const float* rowp =
                            &ys[((cc * YT + od + kd) * YT + (oh + kh)) * YW + ow0];
                        const float v0 = rowp[0], v1 = rowp[1], v2 = rowp[2];
                        const float v3 = rowp[3], v4 = rowp[4], v5 = rowp[5];
                        const float wa = wr[kd * 9 + kh * 3 + 0];
                        const float wb = wr[kd * 9 + kh * 3 + 1];
                        const float wc = wr[kd * 9 + kh * 3 + 2];
                        a0 += wa * v0 + wb * v1 + wc * v2;
                        a1 += wa * v1 + wb * v2 + wc * v3;
                        a2 += wa * v2 + wb * v3 + wc * v4;
                        a3 += wa * v3 + wb * v4 + wc * v5;
                    }
            }
        }
        __syncthreads();   // before next group overwrites ys
    }

    if (tid < 128) {
        const int gd = d0 + od, gh = h0 + oh, gw = w0 + ow0;
        *(float4*)&out[(gd * 96 + gh) * 96 + gw] = make_float4(a0, a1, a2, a3);
    }
}

extern "C" void kernel_launch(void* const* d_in, const int* in_sizes, int n_in,
                              void* d_out, int out_size, void* d_ws, size_t ws_size,
                              hipStream_t stream)
{
    const float* x  = (const float*)d_in[0];
    const float* b  = (const float*)d_in[1];
    const float* A  = (const float*)d_in[2];
    const float* W1 = (const float*)d_in[3];
    const float* b1 = (const float*)d_in[4];
    const float* W2 = (const float*)d_in[5];
    const float* b2 = (const float*)d_in[6];
    float* out = (float*)d_out;

    // workspace partition
    float* cur  = (float*)d_ws;                        // 27*PATCH
    float* xnxt = cur + (size_t)NPAT * PATCH;          // VOL

    const int gsGrid = PATCH / 256;     // 432
    const int fGrid  = 12 * 12 * 12;    // 1728

    // iteration 1
    gs_sweep<<<gsGrid, 256, 0, stream>>>(x, b, A, cur);
    fused_conv<<<fGrid, 256, 0, stream>>>(cur, W1, b1, W2, b2, xnxt);
    // iteration 2
    gs_sweep<<<gsGrid, 256, 0, stream>>>(xnxt, b, A, cur);
    fused_conv<<<fGrid, 256, 0, stream>>>(cur, W1, b1, W2, b2, out);
}